// Round 2
// baseline (581.074 us; speedup 1.0000x reference)
//
#include <hip/hip_runtime.h>
#include <hip/hip_cooperative_groups.h>

// z_{t+1} = z_t @ K, T=256, B=256, D=512. out[b,t,d] = (z0 @ K^{t+1})[b,d], fp32.
//
// SINGLE cooperative kernel: prep + 8 ladder stages + output phase, separated
// by grid.sync() (device-scope fences handle cross-XCD L2 coherence). This
// removes ~9 kernel boundaries (launch gap + full L2 flush each) that R1
// showed dominate the sequential ladder.
//
// Algorithm (unchanged from R1): chunked matrix powers c=16 (depth-8 ladder,
// bf16x3 split precision), U_j = z0 @ K^{16j} built by doubling batched into
// the K^32/K^64/K^128 squaring stages (shared B panel), then fully parallel
// out[16j+i-1] = U_j @ K^i (plain bf16).
//
// ALL intermediates fragment-packed: 1KB chunks = exactly what 64 lanes of one
// 16x16x32 MFMA fragment read (elem = chunk*512 + lane*8 + j). A-operands load
// straight from global (coalesced dwordx4); B panels are CONTIGUOUS in global
// -> staged as consecutive 1KB gll16's, whole K=512 panel at once -> ONE
// barrier per K-loop. Slot layout (u16): [Apk-hi|Apk-lo|Bpk-hi|Bpk-lo].
// Dead forms elided via rowmask/tlomask.

namespace cg = cooperative_groups;

typedef unsigned short u16;
typedef unsigned int u32;
typedef __bf16 bf16x8 __attribute__((ext_vector_type(8)));
typedef float f32x4 __attribute__((ext_vector_type(4)));
typedef u16 u16x4 __attribute__((ext_vector_type(4)));
typedef u16 u16x8 __attribute__((ext_vector_type(8)));

#define MAT 262144    /* 512*512 elems */
#define SLOT 1048576  /* 4*MAT u16 per power slot */
#define WSLOT 131072  /* 256*512 */

__device__ __forceinline__ u16 f2b(float f) {  // fp32 -> bf16 (RNE)
  u32 x = __float_as_uint(f);
  return (u16)((x + 0x7fffu + ((x >> 16) & 1u)) >> 16);
}
__device__ __forceinline__ float b2f(u16 u) { return __uint_as_float(((u32)u) << 16); }

// fragment-packed index for element (r, k), K-dim = 512
__device__ __forceinline__ size_t pidx(int r, int k) {
  return (size_t)(((r >> 4) * 16 + (k >> 5)) * 512 + ((k >> 3) & 3) * 128 + (r & 15) * 8 + (k & 7));
}

__device__ __forceinline__ void gll16(const void* g, void* l) {
  __builtin_amdgcn_global_load_lds((__attribute__((address_space(1))) void*)(void*)g,
                                   (__attribute__((address_space(3))) void*)l, 16, 0, 0);
}

// ---- prep job: pack K into slot0 (4 forms); split z0 -> U_0 hi/lo ----
__device__ __forceinline__ void prep_job(int b, int tid, const float* __restrict__ Kc,
                                         const float* __restrict__ z0, u16* __restrict__ P,
                                         u16* __restrict__ Uh, u16* __restrict__ Ul) {
  if (b < 64) {
    int r0 = (b >> 3) * 64, c0b = (b & 7) * 64;
#pragma unroll
    for (int q = 0; q < 2; ++q) {
      int g = q * 256 + tid;            // 512 groups: 64 rows x 8 col-groups
      int r = r0 + (g >> 3), c0 = c0b + (g & 7) * 8;
      float4 v0 = *(const float4*)(Kc + (size_t)r * 512 + c0);
      float4 v1 = *(const float4*)(Kc + (size_t)r * 512 + c0 + 4);
      float v[8] = {v0.x, v0.y, v0.z, v0.w, v1.x, v1.y, v1.z, v1.w};
      u16x8 h8, l8v;
#pragma unroll
      for (int j = 0; j < 8; ++j) {
        u16 h = f2b(v[j]);
        h8[j] = h;
        l8v[j] = f2b(v[j] - b2f(h));
        size_t ib = pidx(c0 + j, r);    // transposed form, scalar
        P[2 * MAT + ib] = h;
        P[3 * MAT + ib] = l8v[j];
      }
      size_t ia = pidx(r, c0);          // row form, contiguous 8 -> 16B stores
      *(u16x8*)(P + ia) = h8;
      *(u16x8*)(P + MAT + ia) = l8v;
    }
  } else {
    int idb = b - 64;  // 16 blocks x 4 iters x 256 threads x 8 elems = 131072
#pragma unroll
    for (int q = 0; q < 4; ++q) {
      int g = (idb * 4 + q) * 256 + tid;
      int r = g >> 6, c0 = (g & 63) * 8;
      float4 v0 = *(const float4*)(z0 + (size_t)r * 512 + c0);
      float4 v1 = *(const float4*)(z0 + (size_t)r * 512 + c0 + 4);
      float v[8] = {v0.x, v0.y, v0.z, v0.w, v1.x, v1.y, v1.z, v1.w};
      u16x8 h8, l8v;
#pragma unroll
      for (int j = 0; j < 8; ++j) {
        u16 h = f2b(v[j]);
        h8[j] = h;
        l8v[j] = f2b(v[j] - b2f(h));
      }
      size_t ia = pidx(r, c0);
      *(u16x8*)(Uh + ia) = h8;
      *(u16x8*)(Ul + ia) = l8v;
    }
  }
}

// ---- ladder stage job: one shared B panel (hi+lo, 64KB LDS, ONE barrier).
// y < 8*nfull : full DxD job (C 4-form slot, writes gated by rowmask/tlomask).
// y >= 8*nfull: U job u=(y-8*nfull)>>2, 256-row quarter GEMM, row hi/lo only.
// All jobs bf16x3 split: acc += ah*bh + al*bh + ah*bl.
__device__ __forceinline__ void stage_job(
    u16* Bs, int tid, int x, int y, int z,
    const u16* __restrict__ fA, long fAstr, u16* __restrict__ fC, long fCstr,
    const u16* __restrict__ Bh, int nfullv, int rowmask, int tlomask,
    const u16* __restrict__ UA, u16* __restrict__ UC) {
  const u16 *Ah, *Al;
  u16 *Ch, *Clo, *CTh, *CTl;
  int m0;
  bool full = (y < 8 * nfullv);
  bool wrow, wtlo;
  if (full) {
    Ah = fA + (size_t)z * fAstr;
    Al = Ah + MAT;
    Ch = fC + (size_t)z * fCstr;
    Clo = Ch + MAT;
    CTh = Ch + 2 * MAT;
    CTl = Ch + 3 * MAT;
    m0 = y * 64;
    wrow = (rowmask >> z) & 1;
    wtlo = (tlomask >> z) & 1;
  } else {
    int yy = y - 8 * nfullv;
    int u = yy >> 2;
    Ah = UA + (size_t)u * WSLOT;
    Al = Ah + 16 * (size_t)WSLOT;
    Ch = UC + (size_t)u * WSLOT;
    Clo = Ch + 16 * (size_t)WSLOT;
    CTh = CTl = nullptr;
    m0 = (yy & 3) * 64;
    wrow = true;
    wtlo = false;
  }
  const u16* Bl = Bh + MAT;
  int n0 = x * 32;
  int wv = tid >> 6, lane = tid & 63;
  int mrow = lane & 15, quad = lane >> 4;
  int l8 = lane * 8;
  int nchunk0 = n0 >> 4;                 // 2 nchunks x 16 kchunks = 32 chunks/form
  const u16* ph = Bh + (size_t)nchunk0 * 16 * 512;  // contiguous 32KB panel
  const u16* pl = Bl + (size_t)nchunk0 * 16 * 512;
#pragma unroll
  for (int i = 0; i < 8; ++i) {          // wave wv stages chunks wv*8+i (hi & lo)
    int ch = wv * 8 + i;
    gll16(ph + (size_t)ch * 512 + l8, Bs + ch * 512);
    gll16(pl + (size_t)ch * 512 + l8, Bs + 16384 + ch * 512);
  }
  __syncthreads();                       // the ONLY barrier in the K-loop
  int mc = (m0 >> 4) + wv;               // wave-tile 16x32 (4-way m-split)
  f32x4 acc[2] = {};
#pragma unroll 4
  for (int kt = 0; kt < 16; ++kt) {
    size_t co = (size_t)(mc * 16 + kt) * 512 + l8;
    bf16x8 ah = *(const bf16x8*)(Ah + co);
    bf16x8 al = *(const bf16x8*)(Al + co);
#pragma unroll
    for (int nt = 0; nt < 2; ++nt) {
      bf16x8 bh = *(const bf16x8*)(Bs + (nt * 16 + kt) * 512 + l8);
      bf16x8 bl = *(const bf16x8*)(Bs + 16384 + (nt * 16 + kt) * 512 + l8);
      acc[nt] = __builtin_amdgcn_mfma_f32_16x16x32_bf16(ah, bh, acc[nt], 0, 0, 0);
      acc[nt] = __builtin_amdgcn_mfma_f32_16x16x32_bf16(al, bh, acc[nt], 0, 0, 0);
      acc[nt] = __builtin_amdgcn_mfma_f32_16x16x32_bf16(ah, bl, acc[nt], 0, 0, 0);
    }
  }
  // C/D layout: col = lane&15, row = quad*4 + reg
  int mbase = m0 + wv * 16 + quad * 4;
#pragma unroll
  for (int nt = 0; nt < 2; ++nt) {
    int n = n0 + nt * 16 + mrow;
    u16x4 h4, l4;
#pragma unroll
    for (int r = 0; r < 4; ++r) {
      float v = acc[nt][r];
      u16 h = f2b(v);
      h4[r] = h;
      l4[r] = f2b(v - b2f(h));
    }
    if (wrow) {
#pragma unroll
      for (int r = 0; r < 4; ++r) {
        size_t ia = pidx(mbase + r, n);
        Ch[ia] = h4[r];
        Clo[ia] = l4[r];
      }
    }
    if (full) {
      size_t ib = pidx(n, mbase);        // 4 consecutive u16 (m&7 = quad&1*4 + r)
      *(u16x4*)(CTh + ib) = h4;
      if (wtlo) *(u16x4*)(CTl + ib) = l4;
    }
  }
}

// ---- output job: out[:, z, :] = U_{z>>4} @ K^{(z&15)+1}, plain bf16.
// 256x64 tile, whole-K panel (64KB) staged once, ONE barrier, 4-way m-split.
__device__ __forceinline__ void out_job(u16* Bs, int tid, int x, int z,
                                        const u16* __restrict__ Wb,
                                        const u16* __restrict__ PT0,
                                        float* __restrict__ out) {
  const u16* A = Wb + (size_t)(z >> 4) * WSLOT;
  const u16* Bt = PT0 + (size_t)(z & 15) * SLOT;
  int n0 = x * 64;
  int wv = tid >> 6, lane = tid & 63;
  int mrow = lane & 15, quad = lane >> 4;
  int l8 = lane * 8;
  const u16* pb = Bt + (size_t)(n0 >> 4) * 16 * 512;  // contiguous 64KB panel
#pragma unroll
  for (int i = 0; i < 16; ++i) {
    int ch = wv * 16 + i;
    gll16(pb + (size_t)ch * 512 + l8, Bs + ch * 512);
  }
  __syncthreads();                       // the ONLY barrier in the K-loop
  int mc0 = wv * 4;                      // wave-tile 64x64
  f32x4 acc[4][4] = {};
#pragma unroll 4
  for (int kt = 0; kt < 16; ++kt) {
    bf16x8 a[4], b[4];
#pragma unroll
    for (int mt = 0; mt < 4; ++mt)
      a[mt] = *(const bf16x8*)(A + (size_t)((mc0 + mt) * 16 + kt) * 512 + l8);
#pragma unroll
    for (int nt = 0; nt < 4; ++nt)
      b[nt] = *(const bf16x8*)(Bs + (nt * 16 + kt) * 512 + l8);
#pragma unroll
    for (int mt = 0; mt < 4; ++mt)
#pragma unroll
      for (int nt = 0; nt < 4; ++nt)
        acc[mt][nt] = __builtin_amdgcn_mfma_f32_16x16x32_bf16(a[mt], b[nt], acc[mt][nt], 0, 0, 0);
  }
#pragma unroll
  for (int mt = 0; mt < 4; ++mt)
#pragma unroll
    for (int nt = 0; nt < 4; ++nt) {
      int gb = wv * 64 + mt * 16 + quad * 4;
      int gd = n0 + nt * 16 + mrow;
#pragma unroll
      for (int r = 0; r < 4; ++r)
        out[((size_t)(gb + r) * 256 + z) * 512 + gd] = acc[mt][nt][r];
    }
}

// per-stage parameters (P slots: 0..15 = K^1..16; 16 = K^32; 17 = K^64; 18 = K^128)
struct SP {
  int asl, astrf, csl, cstrf, bsl, nfull, rm, tm, uoff, ny;
  int nz;
};
__device__ const SP g_sp[8] = {
    {0, 0, 1, 0, 0, 1, 0x1, 0x1, 0, 8, 1},     // K^2
    {0, 1, 2, 1, 1, 1, 0x3, 0x2, 0, 8, 2},     // K^3,K^4
    {0, 1, 4, 1, 3, 1, 0xF, 0x8, 0, 8, 4},     // K^5..8
    {0, 1, 8, 1, 7, 1, 0x80, 0x80, 0, 8, 8},   // K^9..16
    {15, 0, 16, 0, 15, 1, 0x1, 0x1, 1, 12, 1}, // K^32 + U_1
    {16, 0, 17, 0, 16, 1, 0x1, 0x1, 2, 16, 1}, // K^64 + U_{2,3}
    {17, 0, 18, 0, 17, 1, 0x0, 0x1, 4, 24, 1}, // K^128 + U_{4..7}
    {18, 0, 18, 0, 18, 0, 0x0, 0x0, 8, 32, 1}, // U_{8..15}
};

__global__ __launch_bounds__(256, 2) void fused(const float* Kc, const float* z0,
                                                u16* P, u16* Uh, u16* Ul, float* out) {
  __shared__ u16 Bs[32768];  // 64KB: [hi 32 chunks | lo 32 chunks]
  cg::grid_group grid = cg::this_grid();
  int tid = threadIdx.x;
  int nb = gridDim.x, bid = blockIdx.x;

  // stage P: prep (no LDS)
  for (int b = bid; b < 80; b += nb) prep_job(b, tid, Kc, z0, P, Uh, Ul);
  grid.sync();

  // 8 ladder stages
#pragma unroll 1
  for (int s = 0; s < 8; ++s) {
    SP p = g_sp[s];
    const u16* fA = P + (size_t)p.asl * SLOT;
    u16* fC = P + (size_t)p.csl * SLOT;
    const u16* Bh = P + (size_t)p.bsl * SLOT + 2 * MAT;
    long astr = p.astrf ? (long)SLOT : 0;
    long cstr = p.cstrf ? (long)SLOT : 0;
    u16* UC = Uh + (size_t)p.uoff * WSLOT;
    int njobs = 16 * p.ny * p.nz;
    for (int j = bid; j < njobs; j += nb) {
      int x = j & 15, q = j >> 4;
      int y = q % p.ny, z = q / p.ny;
      stage_job(Bs, tid, x, y, z, fA, astr, fC, cstr, Bh, p.nfull, p.rm, p.tm, Uh, UC);
      __syncthreads();  // protect Bs before next job restages
    }
    grid.sync();
  }

  // output phase: 2048 jobs, one per (n-tile, t)
  for (int j = bid; j < 2048; j += nb) {
    out_job(Bs, tid, j & 7, j >> 3, Uh, P + 2 * MAT, out);
    __syncthreads();  // protect Bs before next job restages
  }
}

extern "C" void kernel_launch(void* const* d_in, const int* in_sizes, int n_in,
                              void* d_out, int out_size, void* d_ws, size_t ws_size,
                              hipStream_t stream) {
  const float* Kc = (const float*)d_in[1];
  const float* z0 = (const float*)d_in[0];
  float* out = (float*)d_out;
  // ws layout (u16): Uh[16*WSLOT] | Ul[16*WSLOT] | P[19*SLOT]
  u16* Uh = (u16*)d_ws;
  u16* Ul = Uh + 16 * (size_t)WSLOT;
  u16* P = Ul + 16 * (size_t)WSLOT;

  static int nblk = 0;
  if (!nblk) {
    int per = 0;
    if (hipOccupancyMaxActiveBlocksPerMultiprocessor(&per, (const void*)fused, 256, 0) != hipSuccess || per <= 0)
      per = 2;  // LDS-bound expectation: 64KB -> 2 blocks/CU
    int cap = per * 256;
    nblk = cap < 512 ? cap : 512;
  }
  void* args[] = {(void*)&Kc, (void*)&z0, (void*)&P, (void*)&Uh, (void*)&Ul, (void*)&out};
  hipLaunchCooperativeKernel((const void*)fused, dim3(nblk), dim3(256), args, 0, stream);
}

// Round 3
// 240.562 us; speedup vs baseline: 2.4155x; 2.4155x over previous
//
#include <hip/hip_runtime.h>

// z_{t+1} = z_t @ K, T=256, B=256, D=512. out[b,t,d] = (z0 @ K^{t+1})[b,d], fp32.
//
// Multi-kernel ladder (R1 structure; cooperative fusion measured 2.3x WORSE —
// grid.sync at 512 blocks costs more than kernel boundaries on 8-XCD gfx950).
//
// Chunked matrix powers, c=16 (ladder depth 8, bf16x3 split precision), U_j =
// z0 @ K^{16j} built by doubling batched into the K^32/K^64/K^128 squaring
// stages (shared B panel), then fully parallel out[16j+i-1] = U_j @ K^i.
//
// R2 change: gemm_out stages its B panel in two 32KB halves through one 32KB
// LDS buffer -> 4 blocks/CU (16 waves/CU, was 8) to hide global-A latency and
// fp32 output writes. Ladder kernels unchanged (grid-limited, not occ-limited).
//
// ALL intermediates fragment-packed: 1KB chunks = exactly what 64 lanes of one
// 16x16x32 MFMA fragment read (elem = chunk*512 + lane*8 + j). A-operands load
// straight from global (coalesced dwordx4); B panels CONTIGUOUS in global ->
// staged as consecutive 1KB gll16's. Slot layout: [Apk-hi|Apk-lo|Bpk-hi|Bpk-lo].
// Dead forms elided via rowmask/tlomask.

typedef unsigned short u16;
typedef unsigned int u32;
typedef __bf16 bf16x8 __attribute__((ext_vector_type(8)));
typedef float f32x4 __attribute__((ext_vector_type(4)));
typedef u16 u16x4 __attribute__((ext_vector_type(4)));
typedef u16 u16x8 __attribute__((ext_vector_type(8)));

#define MAT 262144    /* 512*512 elems */
#define SLOT 1048576  /* 4*MAT u16 per power slot */
#define WSLOT 131072  /* 256*512 */

__device__ __forceinline__ u16 f2b(float f) {  // fp32 -> bf16 (RNE)
  u32 x = __float_as_uint(f);
  return (u16)((x + 0x7fffu + ((x >> 16) & 1u)) >> 16);
}
__device__ __forceinline__ float b2f(u16 u) { return __uint_as_float(((u32)u) << 16); }

// fragment-packed index for element (r, k), K-dim = 512
__device__ __forceinline__ size_t pidx(int r, int k) {
  return (size_t)(((r >> 4) * 16 + (k >> 5)) * 512 + ((k >> 3) & 3) * 128 + (r & 15) * 8 + (k & 7));
}

__device__ __forceinline__ void gll16(const void* g, void* l) {
  __builtin_amdgcn_global_load_lds((__attribute__((address_space(1))) void*)(void*)g,
                                   (__attribute__((address_space(3))) void*)l, 16, 0, 0);
}

// ---- prep: pack K into slot0 (4 forms); split z0 -> U_0 hi (Uh) + lo (Ul) ----
__global__ __launch_bounds__(256) void prep_kernel(const float* __restrict__ Kc,
                                                   const float* __restrict__ z0,
                                                   u16* __restrict__ P,
                                                   u16* __restrict__ Uh,
                                                   u16* __restrict__ Ul) {
  int tid = threadIdx.x, b = blockIdx.x;
  if (b < 64) {
    int r0 = (b >> 3) * 64, c0b = (b & 7) * 64;
#pragma unroll
    for (int q = 0; q < 2; ++q) {
      int g = q * 256 + tid;            // 512 groups: 64 rows x 8 col-groups
      int r = r0 + (g >> 3), c0 = c0b + (g & 7) * 8;
      float4 v0 = *(const float4*)(Kc + (size_t)r * 512 + c0);
      float4 v1 = *(const float4*)(Kc + (size_t)r * 512 + c0 + 4);
      float v[8] = {v0.x, v0.y, v0.z, v0.w, v1.x, v1.y, v1.z, v1.w};
      u16x8 h8, l8v;
#pragma unroll
      for (int j = 0; j < 8; ++j) {
        u16 h = f2b(v[j]);
        h8[j] = h;
        l8v[j] = f2b(v[j] - b2f(h));
        size_t ib = pidx(c0 + j, r);    // transposed form, scalar
        P[2 * MAT + ib] = h;
        P[3 * MAT + ib] = l8v[j];
      }
      size_t ia = pidx(r, c0);          // row form, contiguous 8 -> 16B stores
      *(u16x8*)(P + ia) = h8;
      *(u16x8*)(P + MAT + ia) = l8v;
    }
  } else {
    int idb = b - 64;  // 16 blocks x 4 iters x 256 threads x 8 elems = 131072
#pragma unroll
    for (int q = 0; q < 4; ++q) {
      int g = (idb * 4 + q) * 256 + tid;
      int r = g >> 6, c0 = (g & 63) * 8;
      float4 v0 = *(const float4*)(z0 + (size_t)r * 512 + c0);
      float4 v1 = *(const float4*)(z0 + (size_t)r * 512 + c0 + 4);
      float v[8] = {v0.x, v0.y, v0.z, v0.w, v1.x, v1.y, v1.z, v1.w};
      u16x8 h8, l8v;
#pragma unroll
      for (int j = 0; j < 8; ++j) {
        u16 h = f2b(v[j]);
        h8[j] = h;
        l8v[j] = f2b(v[j] - b2f(h));
      }
      size_t ia = pidx(r, c0);
      *(u16x8*)(Uh + ia) = h8;
      *(u16x8*)(Ul + ia) = l8v;
    }
  }
}

// ---- merged ladder stage: one shared B panel (hi+lo, 64KB LDS, ONE barrier).
// blockIdx.y < 8*nfull  : full DxD job, C 4-form slot (writes gated by
//                         rowmask/tlomask bit z; T-hi always written).
// blockIdx.y >= 8*nfull : U job u = (y-8*nfull)>>2, 256-row quarter GEMM,
//                         row hi/lo forms only.
// All jobs bf16x3 split: acc += ah*bh + al*bh + ah*bl.
__global__ __launch_bounds__(256, 2) void gemm_stage(
    const u16* __restrict__ fA, long fAstr,
    u16* __restrict__ fC, long fCstr,
    const u16* __restrict__ Bh, int nfull, int rowmask, int tlomask,
    const u16* __restrict__ UA, u16* __restrict__ UC) {
  __shared__ u16 Bs[32768];  // [hi 32 chunks | lo 32 chunks] = 64KB
  int z = blockIdx.z, y = blockIdx.y;
  const u16 *Ah, *Al;
  u16 *Ch, *Clo, *CTh, *CTl;
  int m0;
  bool full = (y < 8 * nfull);
  bool wrow, wtlo;
  if (full) {
    Ah = fA + (size_t)z * fAstr;
    Al = Ah + MAT;
    Ch = fC + (size_t)z * fCstr;
    Clo = Ch + MAT;
    CTh = Ch + 2 * MAT;
    CTl = Ch + 3 * MAT;
    m0 = y * 64;
    wrow = (rowmask >> z) & 1;
    wtlo = (tlomask >> z) & 1;
  } else {
    int yy = y - 8 * nfull;
    int u = yy >> 2;
    Ah = UA + (size_t)u * WSLOT;
    Al = Ah + 16 * (size_t)WSLOT;
    Ch = UC + (size_t)u * WSLOT;
    Clo = Ch + 16 * (size_t)WSLOT;
    CTh = CTl = nullptr;
    m0 = (yy & 3) * 64;
    wrow = true;
    wtlo = false;
  }
  const u16* Bl = Bh + MAT;
  int tid = threadIdx.x;
  int n0 = blockIdx.x * 32;
  int wv = tid >> 6, lane = tid & 63;
  int mrow = lane & 15, quad = lane >> 4;
  int l8 = lane * 8;
  int nchunk0 = n0 >> 4;                 // 2 nchunks x 16 kchunks = 32 chunks/form
  const u16* ph = Bh + (size_t)nchunk0 * 16 * 512;  // contiguous 32KB panel
  const u16* pl = Bl + (size_t)nchunk0 * 16 * 512;
#pragma unroll
  for (int i = 0; i < 8; ++i) {          // wave wv stages chunks wv*8+i (hi & lo)
    int ch = wv * 8 + i;
    gll16(ph + (size_t)ch * 512 + l8, Bs + ch * 512);
    gll16(pl + (size_t)ch * 512 + l8, Bs + 16384 + ch * 512);
  }
  __syncthreads();                       // the ONLY barrier
  int mc = (m0 >> 4) + wv;               // wave-tile 16x32 (4-way m-split)
  f32x4 acc[2] = {};
#pragma unroll 4
  for (int kt = 0; kt < 16; ++kt) {
    size_t co = (size_t)(mc * 16 + kt) * 512 + l8;
    bf16x8 ah = *(const bf16x8*)(Ah + co);
    bf16x8 al = *(const bf16x8*)(Al + co);
#pragma unroll
    for (int nt = 0; nt < 2; ++nt) {
      bf16x8 bh = *(const bf16x8*)(Bs + (nt * 16 + kt) * 512 + l8);
      bf16x8 bl = *(const bf16x8*)(Bs + 16384 + (nt * 16 + kt) * 512 + l8);
      acc[nt] = __builtin_amdgcn_mfma_f32_16x16x32_bf16(ah, bh, acc[nt], 0, 0, 0);
      acc[nt] = __builtin_amdgcn_mfma_f32_16x16x32_bf16(al, bh, acc[nt], 0, 0, 0);
      acc[nt] = __builtin_amdgcn_mfma_f32_16x16x32_bf16(ah, bl, acc[nt], 0, 0, 0);
    }
  }
  // C/D layout: col = lane&15, row = quad*4 + reg
  int mbase = m0 + wv * 16 + quad * 4;
#pragma unroll
  for (int nt = 0; nt < 2; ++nt) {
    int n = n0 + nt * 16 + mrow;
    u16x4 h4, l4;
#pragma unroll
    for (int r = 0; r < 4; ++r) {
      float v = acc[nt][r];
      u16 h = f2b(v);
      h4[r] = h;
      l4[r] = f2b(v - b2f(h));
    }
    if (wrow) {
#pragma unroll
      for (int r = 0; r < 4; ++r) {
        size_t ia = pidx(mbase + r, n);
        Ch[ia] = h4[r];
        Clo[ia] = l4[r];
      }
    }
    if (full) {
      size_t ib = pidx(n, mbase);        // 4 consecutive u16 (m&7 = quad&1*4 + r)
      *(u16x4*)(CTh + ib) = h4;
      if (wtlo) *(u16x4*)(CTl + ib) = l4;
    }
  }
}

// ---- parallel phase: out[:, z, :] = U_{z>>4} @ K^{(z&15)+1}, plain bf16.
// 256x64 tile. B panel staged in TWO 32KB halves through one 32KB buffer ->
// 4 blocks/CU (16 waves/CU) for latency hiding. 3 barriers. 4-way m-split.
__global__ __launch_bounds__(256, 4) void gemm_out(const u16* __restrict__ Wb,
                                                   const u16* __restrict__ PT0,
                                                   float* __restrict__ out) {
  __shared__ u16 Bs[16384];  // 32KB: 4 nchunks x 8 kchunks
  int z = blockIdx.z;
  const u16* A = Wb + (size_t)(z >> 4) * WSLOT;
  const u16* Bt = PT0 + (size_t)(z & 15) * SLOT;
  int tid = threadIdx.x;
  int n0 = blockIdx.x * 64;
  int wv = tid >> 6, lane = tid & 63;
  int mrow = lane & 15, quad = lane >> 4;
  int l8 = lane * 8;
  const u16* pb = Bt + (size_t)(n0 >> 4) * 16 * 512;  // contiguous 64KB panel
  int mc0 = wv * 4;                      // wave-tile 64x64
  f32x4 acc[4][4] = {};
#pragma unroll
  for (int h = 0; h < 2; ++h) {
    // stage half h: kchunks 8h..8h+7 of each of 4 nchunks -> 32 chunks of 1KB
#pragma unroll
    for (int i = 0; i < 8; ++i) {
      int c = wv * 8 + i;                // c = nc*8 + kc, nc = c>>3, kc = c&7
      int nc = c >> 3, kc = c & 7;
      gll16(pb + (size_t)(nc * 16 + h * 8 + kc) * 512 + l8, Bs + c * 512);
    }
    __syncthreads();                     // staging done (drains vmcnt)
#pragma unroll 4
    for (int kt = 0; kt < 8; ++kt) {
      int ktg = h * 8 + kt;
      bf16x8 a[4], b[4];
#pragma unroll
      for (int mt = 0; mt < 4; ++mt)
        a[mt] = *(const bf16x8*)(A + (size_t)((mc0 + mt) * 16 + ktg) * 512 + l8);
#pragma unroll
      for (int nt = 0; nt < 4; ++nt)
        b[nt] = *(const bf16x8*)(Bs + (nt * 8 + kt) * 512 + l8);
#pragma unroll
      for (int mt = 0; mt < 4; ++mt)
#pragma unroll
        for (int nt = 0; nt < 4; ++nt)
          acc[mt][nt] = __builtin_amdgcn_mfma_f32_16x16x32_bf16(a[mt], b[nt], acc[mt][nt], 0, 0, 0);
    }
    if (h == 0) __syncthreads();         // all waves done reading before restage
  }
#pragma unroll
  for (int mt = 0; mt < 4; ++mt)
#pragma unroll
    for (int nt = 0; nt < 4; ++nt) {
      int gb = wv * 64 + mt * 16 + quad * 4;
      int gd = n0 + nt * 16 + mrow;
#pragma unroll
      for (int r = 0; r < 4; ++r)
        out[((size_t)(gb + r) * 256 + z) * 512 + gd] = acc[mt][nt][r];
    }
}

extern "C" void kernel_launch(void* const* d_in, const int* in_sizes, int n_in,
                              void* d_out, int out_size, void* d_ws, size_t ws_size,
                              hipStream_t stream) {
  const float* z0 = (const float*)d_in[0];
  const float* Kc = (const float*)d_in[1];
  float* out = (float*)d_out;
  // ws layout (u16): Uh[16*WSLOT] | Ul[16*WSLOT] | P[19*SLOT]
  // P slots: 0..15 = K^1..K^16; 16 = K^32; 17 = K^64; 18 = K^128
  u16* Uh = (u16*)d_ws;
  u16* Ul = Uh + 16 * (size_t)WSLOT;
  u16* P = Ul + 16 * (size_t)WSLOT;
  auto S = [&](int s) { return P + (size_t)s * SLOT; };
  dim3 blk(256);

  prep_kernel<<<80, blk, 0, stream>>>(Kc, z0, P, Uh, Ul);
  // small powers: K^2; {K^3,K^4}; {K^5..8}; {K^9..16}
  gemm_stage<<<dim3(16, 8, 1), blk, 0, stream>>>(S(0), 0, S(1), 0, S(0) + 2 * MAT, 1, 0x1, 0x1, nullptr, nullptr);
  gemm_stage<<<dim3(16, 8, 2), blk, 0, stream>>>(S(0), SLOT, S(2), SLOT, S(1) + 2 * MAT, 1, 0x3, 0x2, nullptr, nullptr);
  gemm_stage<<<dim3(16, 8, 4), blk, 0, stream>>>(S(0), SLOT, S(4), SLOT, S(3) + 2 * MAT, 1, 0xF, 0x8, nullptr, nullptr);
  gemm_stage<<<dim3(16, 8, 8), blk, 0, stream>>>(S(0), SLOT, S(8), SLOT, S(7) + 2 * MAT, 1, 0x80, 0x80, nullptr, nullptr);
  // doubling stages: power squaring + U-doubling share one B panel per launch
  // s5: K^32 = K^16@K^16  +  U_1 = U_0@K^16
  gemm_stage<<<dim3(16, 12, 1), blk, 0, stream>>>(S(15), 0, S(16), 0, S(15) + 2 * MAT, 1, 0x1, 0x1, Uh, Uh + 1 * (size_t)WSLOT);
  // s6: K^64 = K^32@K^32  +  U_{2,3} = U_{0,1}@K^32
  gemm_stage<<<dim3(16, 16, 1), blk, 0, stream>>>(S(16), 0, S(17), 0, S(16) + 2 * MAT, 1, 0x1, 0x1, Uh, Uh + 2 * (size_t)WSLOT);
  // s7: K^128 = K^64@K^64  +  U_{4..7} = U_{0..3}@K^64   (K^128 row forms unused)
  gemm_stage<<<dim3(16, 24, 1), blk, 0, stream>>>(S(17), 0, S(18), 0, S(17) + 2 * MAT, 1, 0x0, 0x1, Uh, Uh + 4 * (size_t)WSLOT);
  // s8: U_{8..15} = U_{0..7}@K^128
  gemm_stage<<<dim3(16, 32, 1), blk, 0, stream>>>(S(18), 0, S(18), 0, S(18) + 2 * MAT, 0, 0x0, 0x0, Uh, Uh + 8 * (size_t)WSLOT);
  // parallel phase: 2048 WGs, one per (n-tile, t)
  gemm_out<<<dim3(8, 1, 256), blk, 0, stream>>>(Uh, P + 2 * MAT, out);
}